// Round 13
// baseline (95.503 us; speedup 1.0000x reference)
//
#include <hip/hip_runtime.h>
#include <stdint.h>

// Y = tanh(X @ W + b):  M=65536 (8*64*128), K=512, N=512, all fp32.
// R13 = R12 with the two bugs fixed:
//  (1) R12's wave-private A tile was UNSWIZZLED: write banks = 8k mod 32
//      (16-way), read 32 lanes on 4 banks (16-way) -> 5.2M conflict cycles
//      (~10 cy/instr) which serialized the LDS pipe. Now slot = c ^ K(r),
//      K(r) = (r>>1)&3 -- enumeration-verified: every 16-lane phase hits each
//      16B granule exactly 2x (free) on both writes and all 4 reads.
//  (2) (256,2) -> (256,3): 12 waves/CU (148 regs <= cap 170, no spill).
// Structure (from R12): wave tile 32x128; B NEVER in LDS (fragment-ordered
// bf16 image read as perfectly-coalesced 1KB dwordx4 from L2); A via
// reg->cvt->wave-private LDS (zero barriers anywhere); counted vmcnt
// invariant queue [B(t):8, A(t+1):4] -> VM(12)/VM(8), 0 only at tail.

typedef short bf16x8 __attribute__((ext_vector_type(8)));
typedef float f32x16 __attribute__((ext_vector_type(16)));

#define KTOT 512
#define NTOT 512
#define WT_BYTES   524288ull      // 512*512*2
#define WS_NEEDED  WT_BYTES

__device__ __forceinline__ uint32_t pk2(float a, float b) {
  uint16_t lo = __builtin_bit_cast(uint16_t, (__bf16)a);   // RNE
  uint16_t hi = __builtin_bit_cast(uint16_t, (__bf16)b);
  return (uint32_t)lo | ((uint32_t)hi << 16);
}

__device__ __forceinline__ float fast_tanh(float z) {
  float t = __builtin_amdgcn_exp2f(z * 2.8853900817779268f);
  return 1.0f - 2.0f * __builtin_amdgcn_rcpf(t + 1.0f);
}

// ---- pass 1: W fp32 [k][n] -> bf16 fragment-order image ----
// chunk c (0..32767): lane=c&63, kk=(c>>6)&1, step=(c>>7)&15, nf=(c>>11)&3,
// bq=c>>13. 16B = 8 bf16 of column (bq*128+nf*32+(lane&31)),
// k = step*32 + kk*16 + (lane>>5)*8 + [0..7]. Stored flat at Wt + c*16.
__global__ __launch_bounds__(256)
void cvtW_kernel(const float* __restrict__ W, uint8_t* __restrict__ Wt) {
  const int c    = blockIdx.x * 256 + threadIdx.x;   // 0..32767
  const int lane = c & 63;
  const int kk   = (c >> 6) & 1;
  const int st   = (c >> 7) & 15;
  const int nf   = (c >> 11) & 3;
  const int bq   = c >> 13;
  const int col  = bq * 128 + nf * 32 + (lane & 31);
  const int kb   = st * 32 + kk * 16 + (lane >> 5) * 8;
  float e[8];
#pragma unroll
  for (int i = 0; i < 8; ++i) e[i] = W[(size_t)(kb + i) * NTOT + col];
  *(uint4*)(Wt + (size_t)c * 16) =
      make_uint4(pk2(e[0], e[1]), pk2(e[2], e[3]),
                 pk2(e[4], e[5]), pk2(e[6], e[7]));
}

// ---------------- pass 2: barrier-free GEMM + bias + tanh ----------------
__global__ __launch_bounds__(256, 3)
void hotdd_fused(const float* __restrict__ X, const uint8_t* __restrict__ Wt,
                 const float* __restrict__ Bv, float* __restrict__ Y) {
  __shared__ uint8_t Ab[2][8192];   // per buf: 4 waves x [32 rows][4 slots x 16B]

  // XCD swizzle: the 4 bn-blocks sharing an X strip -> same XCD, adjacent.
  const int d  = blockIdx.x;
  const int bm = ((d >> 5) << 3) | (d & 7);   // 0..511
  const int bn = (d >> 3) & 3;                // 0..3

  const int tid  = threadIdx.x;
  const int lane = tid & 63;
  const int wv   = tid >> 6;
  const int lo5  = lane & 31;
  const int hi1  = lane >> 5;

  // ---- A staging (wave-private strip = rows bm*128 + wv*32 + [0..31]):
  // write: lane -> row r=lane>>1, half h=lane&1, chunks 2h, 2h+1;
  //        LDS slot = chunk ^ K(r), K(r) = (r>>1)&3  (conflict-free, verified)
  const int arow  = lane >> 1;
  const int ahalf = lane & 1;
  const float* pA = X + (size_t)(bm * 128 + wv * 32 + arow) * KTOT + ahalf * 16;
  const int akw  = (arow >> 1) & 3;
  const int awr0 = wv * 2048 + arow * 64 + ((((ahalf << 1)) ^ akw) << 4);
  // second chunk slot = first ^ 1 -> byte addr ^ 16
  // read: lane -> row lo5; fa0 chunk hi1, fa1 chunk 2|hi1; slot = c ^ K(lo5)
  const int akr = (lo5 >> 1) & 3;
  const int ard = wv * 2048 + lo5 * 64;
  const int aro0 = (hi1 ^ akr) << 4;
  const int aro1 = ((2 | hi1) ^ akr) << 4;

  // ---- B fragment pointers (per nf sub-tile of 32 cols)
  const uint8_t* pB0 = Wt + ((size_t)(bn * 4 + 0) << 15) + lane * 16;
  const uint8_t* pB1 = pB0 + 32768;
  const uint8_t* pB2 = pB0 + 65536;
  const uint8_t* pB3 = pB0 + 98304;

  float4 rs0, rs1, rs2, rs3;                    // A staging regs
  bf16x8 a0, a1, a2, a3, a4, a5, a6, a7;        // B set A  [kk*4+nf]
  bf16x8 b0, b1, b2, b3, b4, b5, b6, b7;        // B set B
  f32x16 acc0 = {}, acc1 = {}, acc2 = {}, acc3 = {};

#define SEP()  asm volatile("" ::: "memory")
#define VM(N)  asm volatile("s_waitcnt vmcnt(" #N ")" ::: "memory")

#define LOADA(OFF) do {                                                       \
    rs0 = *(const float4*)(pA + (OFF));                                       \
    rs1 = *(const float4*)(pA + (OFF) + 4);                                   \
    rs2 = *(const float4*)(pA + (OFF) + 8);                                   \
    rs3 = *(const float4*)(pA + (OFF) + 12);                                  \
    SEP();                                                                    \
  } while (0)

#define LOADB(B0,B1,B2,B3,B4,B5,B6,B7, OFF) do {                              \
    B0 = *(const bf16x8*)(pB0 + (OFF));                                       \
    B1 = *(const bf16x8*)(pB1 + (OFF));                                       \
    B2 = *(const bf16x8*)(pB2 + (OFF));                                       \
    B3 = *(const bf16x8*)(pB3 + (OFF));                                       \
    B4 = *(const bf16x8*)(pB0 + (OFF) + 1024);                                \
    B5 = *(const bf16x8*)(pB1 + (OFF) + 1024);                                \
    B6 = *(const bf16x8*)(pB2 + (OFF) + 1024);                                \
    B7 = *(const bf16x8*)(pB3 + (OFF) + 1024);                                \
    SEP();                                                                    \
  } while (0)

#define CVTA(BUF) do {                                                        \
    *(uint4*)(&Ab[BUF][awr0]) =                                               \
        make_uint4(pk2(rs0.x, rs0.y), pk2(rs0.z, rs0.w),                      \
                   pk2(rs1.x, rs1.y), pk2(rs1.z, rs1.w));                     \
    *(uint4*)(&Ab[BUF][awr0 ^ 16]) =                                          \
        make_uint4(pk2(rs2.x, rs2.y), pk2(rs2.z, rs2.w),                      \
                   pk2(rs3.x, rs3.y), pk2(rs3.z, rs3.w));                     \
    SEP();                                                                    \
  } while (0)

#define MFMA8(BUF, B0,B1,B2,B3,B4,B5,B6,B7) do {                              \
    bf16x8 fa0 = *(const bf16x8*)(&Ab[BUF][ard + aro0]);                      \
    acc0 = __builtin_amdgcn_mfma_f32_32x32x16_bf16(fa0, B0, acc0, 0, 0, 0);   \
    acc1 = __builtin_amdgcn_mfma_f32_32x32x16_bf16(fa0, B1, acc1, 0, 0, 0);   \
    acc2 = __builtin_amdgcn_mfma_f32_32x32x16_bf16(fa0, B2, acc2, 0, 0, 0);   \
    acc3 = __builtin_amdgcn_mfma_f32_32x32x16_bf16(fa0, B3, acc3, 0, 0, 0);   \
    bf16x8 fa1 = *(const bf16x8*)(&Ab[BUF][ard + aro1]);                      \
    acc0 = __builtin_amdgcn_mfma_f32_32x32x16_bf16(fa1, B4, acc0, 0, 0, 0);   \
    acc1 = __builtin_amdgcn_mfma_f32_32x32x16_bf16(fa1, B5, acc1, 0, 0, 0);   \
    acc2 = __builtin_amdgcn_mfma_f32_32x32x16_bf16(fa1, B6, acc2, 0, 0, 0);   \
    acc3 = __builtin_amdgcn_mfma_f32_32x32x16_bf16(fa1, B7, acc3, 0, 0, 0);   \
  } while (0)

  // ---- prologue: establish invariant queue [B(0):8, A(1):4]
  LOADA(0);                                  // A(0)
  LOADB(a0,a1,a2,a3,a4,a5,a6,a7, 0);         // B(0)
  VM(8);                                     // A(0) landed
  CVTA(0);                                   // buf0 <- A(0)
  LOADA(32);                                 // A(1)

  // ---- main loop: steps 0..13, two per iter. No barriers anywhere.
#pragma unroll 1
  for (int it = 0; it < 7; ++it) {
    // even step t=2it: compute buf0 x setA; prep buf1, setB
    LOADB(b0,b1,b2,b3,b4,b5,b6,b7, 2048);    // B(t+1)
    VM(12);                                  // B(t) landed
    MFMA8(0, a0,a1,a2,a3,a4,a5,a6,a7);
    VM(8);                                   // A(t+1) landed
    CVTA(1);                                 // buf1 <- A(t+1)
    LOADA(64);                               // A(t+2)
    pB0 += 4096; pB1 += 4096; pB2 += 4096; pB3 += 4096;
    // odd step t+1: compute buf1 x setB; prep buf0, setA
    LOADB(a0,a1,a2,a3,a4,a5,a6,a7, 0);       // B(t+2) (base just advanced)
    VM(12);                                  // B(t+1) landed
    MFMA8(1, b0,b1,b2,b3,b4,b5,b6,b7);
    VM(8);                                   // A(t+2) landed
    CVTA(0);                                 // buf0 <- A(t+2)
    LOADA(96);                               // A(t+3)
    pA += 64;
  }

  // ---- tail: step 14 (no A(16)), step 15 (drain)
  LOADB(b0,b1,b2,b3,b4,b5,b6,b7, 2048);      // B(15)
  VM(12);                                    // B(14) landed
  MFMA8(0, a0,a1,a2,a3,a4,a5,a6,a7);         // step 14
  VM(8);                                     // A(15) landed
  CVTA(1);
  VM(0);                                     // B(15) landed
  MFMA8(1, b0,b1,b2,b3,b4,b5,b6,b7);         // step 15

  // ---- epilogue: bias + tanh + fp32 store
  const int gnb  = bn * 128 + lo5;
  const int rowb = bm * 128 + wv * 32;

#define EPI(ACC, NF) do {                                                     \
    const float bv = Bv[gnb + (NF) * 32];                                     \
    _Pragma("unroll")                                                         \
    for (int r = 0; r < 16; ++r) {                                            \
      const int rl = (r & 3) + ((r >> 2) << 3) + (hi1 << 2);                  \
      Y[(size_t)(rowb + rl) * NTOT + gnb + (NF) * 32] =                       \
          fast_tanh((ACC)[r] + bv);                                           \
    }                                                                         \
  } while (0)

  EPI(acc0, 0);
  EPI(acc1, 1);
  EPI(acc2, 2);
  EPI(acc3, 3);
}

// ---------------- fallback: R1 kernel (146us), used if ws too small ----------
struct Regs {
  float4 a0,a1,a2,a3,a4,a5,a6,a7;
  float4 u0,u1,u2,u3;
  float4 v0,v1,v2,v3;
};

__global__ __launch_bounds__(256, 2)
void hotdd_fallback(const float* __restrict__ X, const float* __restrict__ W,
                    const float* __restrict__ Bv, float* __restrict__ Y) {
  __shared__ char Ab[128 * 64 * 2];
  __shared__ char Bb[128 * 64 * 2];
  const int d  = blockIdx.x;
  const int bm = ((d >> 5) << 3) | (d & 7);
  const int bn = (d >> 3) & 3;
  const int tid  = threadIdx.x;
  const int lane = tid & 63;
  const int wv   = tid >> 6;
  const int wr   = (wv >> 1) * 64;
  const int wc   = (wv & 1) * 64;
  const int lo5  = lane & 31;
  const int hi1  = lane >> 5;
  const int rs   = lo5 & 7;
  const int am   = tid >> 1;
  const int ah   = tid & 1;
  const int amz  = am & 7;
  const int abase = am * 128;
  const float* Ag = X + (size_t)(bm * 128 + am) * KTOT + ah * 32;
  const int kp = lo5;
  const int ng = wv * 32 + hi1 * 16;
  const float* Bg = W + (size_t)(2 * kp) * NTOT + bn * 128 + ng;

#define LOADR(R, K0) do {                                                     \
    const float* ap_ = Ag + (K0);                                             \
    R.a0 = *(const float4*)(ap_ +  0); R.a1 = *(const float4*)(ap_ +  4);     \
    R.a2 = *(const float4*)(ap_ +  8); R.a3 = *(const float4*)(ap_ + 12);     \
    R.a4 = *(const float4*)(ap_ + 16); R.a5 = *(const float4*)(ap_ + 20);     \
    R.a6 = *(const float4*)(ap_ + 24); R.a7 = *(const float4*)(ap_ + 28);     \
    const float* bp_ = Bg + (size_t)(K0) * NTOT;                              \
    R.u0 = *(const float4*)(bp_ +  0); R.u1 = *(const float4*)(bp_ +  4);     \
    R.u2 = *(const float4*)(bp_ +  8); R.u3 = *(const float4*)(bp_ + 12);     \
    R.v0 = *(const float4*)(bp_ + NTOT +  0); R.v1 = *(const float4*)(bp_ + NTOT +  4); \
    R.v2 = *(const float4*)(bp_ + NTOT +  8); R.v3 = *(const float4*)(bp_ + NTOT + 12); \
  } while (0)

#define ASTF(R, J, P, Q)                                                      \
    *(uint4*)(Ab + abase + (((((ah << 2) + (J)) ^ amz)) << 4)) =              \
      make_uint4(pk2(R.P.x, R.P.y), pk2(R.P.z, R.P.w),                        \
                 pk2(R.Q.x, R.Q.y), pk2(R.Q.z, R.Q.w));
#define BSTF(R, I, UV, C)                                                     \
    *(uint32_t*)(Bb + (ng + (I)) * 128 + ((kp << 2) ^ (((I) & 7) << 4))) =    \
      pk2(R.u##UV.C, R.v##UV.C);

#define STORERF(R) do {                                                       \
    ASTF(R, 0, a0, a1) ASTF(R, 1, a2, a3) ASTF(R, 2, a4, a5) ASTF(R, 3, a6, a7)\
    BSTF(R, 0, 0, x) BSTF(R, 1, 0, y) BSTF(R, 2, 0, z) BSTF(R, 3, 0, w)       \
    BSTF(R, 4, 1, x) BSTF(R, 5, 1, y) BSTF(R, 6, 1, z) BSTF(R, 7, 1, w)       \
    BSTF(R, 8, 2, x) BSTF(R, 9, 2, y) BSTF(R,10, 2, z) BSTF(R,11, 2, w)       \
    BSTF(R,12, 3, x) BSTF(R,13, 3, y) BSTF(R,14, 3, z) BSTF(R,15, 3, w)       \
  } while (0)

  f32x16 acc00 = {}, acc01 = {}, acc10 = {}, acc11 = {};
  const char* Ard0 = Ab + (wr + lo5) * 128;
  const char* Ard1 = Ard0 + 32 * 128;
  const char* Brd0 = Bb + (wc + lo5) * 128;
  const char* Brd1 = Brd0 + 32 * 128;

#define MFMA_PHASE_F() do {                                                   \
    _Pragma("unroll")                                                         \
    for (int kk = 0; kk < 4; ++kk) {                                          \
      const int sb = ((((kk << 1) | hi1) ^ rs) << 4);                         \
      bf16x8 fa0 = *(const bf16x8*)(Ard0 + sb);                               \
      bf16x8 fa1 = *(const bf16x8*)(Ard1 + sb);                               \
      bf16x8 fb0 = *(const bf16x8*)(Brd0 + sb);                               \
      bf16x8 fb1 = *(const bf16x8*)(Brd1 + sb);                               \
      acc00 = __builtin_amdgcn_mfma_f32_32x32x16_bf16(fa0, fb0, acc00, 0,0,0);\
      acc01 = __builtin_amdgcn_mfma_f32_32x32x16_bf16(fa0, fb1, acc01, 0,0,0);\
      acc10 = __builtin_amdgcn_mfma_f32_32x32x16_bf16(fa1, fb0, acc10, 0,0,0);\
      acc11 = __builtin_amdgcn_mfma_f32_32x32x16_bf16(fa1, fb1, acc11, 0,0,0);\
    }                                                                         \
  } while (0)

  Regs r0, r1;
  LOADR(r0, 0);
#pragma unroll 1
  for (int s = 0; s < 8; s += 2) {
    STORERF(r0);
    __syncthreads();
    LOADR(r1, (s + 1) * 64);
    MFMA_PHASE_F();
    __syncthreads();
    STORERF(r1);
    __syncthreads();
    if (s + 2 < 8) LOADR(r0, (s + 2) * 64);
    MFMA_PHASE_F();
    __syncthreads();
  }

  const int gn0 = bn * 128 + wc + lo5;
  const int gn1 = gn0 + 32;
  const float bv0 = Bv[gn0];
  const float bv1 = Bv[gn1];

#define EPIF(ACC, MI, GN, BVAL) do {                                          \
    _Pragma("unroll")                                                         \
    for (int r = 0; r < 16; ++r) {                                            \
      const int mloc = wr + (MI) * 32 + (hi1 << 2) + ((r >> 2) << 3) + (r & 3);\
      Y[(size_t)(bm * 128 + mloc) * NTOT + (GN)] = fast_tanh((ACC)[r] + (BVAL));\
    }                                                                         \
  } while (0)

  EPIF(acc00, 0, gn0, bv0);
  EPIF(acc01, 0, gn1, bv1);
  EPIF(acc10, 1, gn0, bv0);
  EPIF(acc11, 1, gn1, bv1);
}

extern "C" void kernel_launch(void* const* d_in, const int* in_sizes, int n_in,
                              void* d_out, int out_size, void* d_ws, size_t ws_size,
                              hipStream_t stream) {
  (void)in_sizes; (void)n_in; (void)out_size;
  const float* X = (const float*)d_in[0];
  const float* W = (const float*)d_in[1];
  const float* b = (const float*)d_in[2];
  float* Y = (float*)d_out;
  if (ws_size >= WS_NEEDED) {
    uint8_t* Wt = (uint8_t*)d_ws;
    hipLaunchKernelGGL(cvtW_kernel, dim3(128),  dim3(256), 0, stream, W, Wt);
    hipLaunchKernelGGL(hotdd_fused, dim3(2048), dim3(256), 0, stream, X, Wt, b, Y);
  } else {
    hipLaunchKernelGGL(hotdd_fallback, dim3(2048), dim3(256), 0, stream, X, W, b, Y);
  }
}

// Round 14
// 80.354 us; speedup vs baseline: 1.1885x; 1.1885x over previous
//
#include <hip/hip_runtime.h>
#include <stdint.h>

// Y = tanh(X @ W + b):  M=65536 (8*64*128), K=512, N=512, all fp32.
// R14 = R9 (best, 78.4us) + A-REGISTER PREFETCH DEPTH 4.
// Diagnosis: R9/R11/R13 all gave A(t+1) only ONE step of own-issue slack
// (~250-500cy) vs ~900cy HBM latency on X -> every step, every wave eats
// uncovered latency and the barrier convoys the block onto the slowest wave.
// (R13's conflict fix proved LDS was NOT the binding pipe: conflicts 5.2M->1M,
// time unchanged. R9 LDS pipe only ~41% busy.)
// Fix: 4 rotating A-reg sets; LOADA(t+4) at step t, consumed at t+3 ->
// 3 steps of slack. Queue invariant at step top: [A(t+1):4, A(t+2):4,
// B(t):2, A(t+3):4]; ONE VM(4) retires A(t+1),A(t+2),B(t) together ->
// CVTA needs no wait. B keeps 1-step slack (W image L2-hot).
// VGPR ~96-110 + 64 AGPR <= cap 170 at (256,3); spill tripwire: WRITE_SIZE.

typedef short bf16x8 __attribute__((ext_vector_type(8)));
typedef float f32x16 __attribute__((ext_vector_type(16)));

#define KTOT 512
#define NTOT 512
#define WT_BYTES   524288ull      // 512*512*2
#define WS_NEEDED  WT_BYTES

typedef __attribute__((address_space(3))) uint8_t lds8;
typedef __attribute__((address_space(1))) const uint8_t glb8;

__device__ __forceinline__ uint32_t pk2(float a, float b) {
  uint16_t lo = __builtin_bit_cast(uint16_t, (__bf16)a);   // RNE
  uint16_t hi = __builtin_bit_cast(uint16_t, (__bf16)b);
  return (uint32_t)lo | ((uint32_t)hi << 16);
}

__device__ __forceinline__ float fast_tanh(float z) {
  float t = __builtin_amdgcn_exp2f(z * 2.8853900817779268f);
  return 1.0f - 2.0f * __builtin_amdgcn_rcpf(t + 1.0f);
}

__device__ __forceinline__ int swz4(int r) { return ((r >> 1) ^ (r >> 3)) & 3; }

// ---- pass 1: W fp32 [k][n] -> bf16 transposed swizzled image, BK=32 tiles --
// 64 tiles (bn*16+s) of 8KB: [r:128 rows][4 slots x 16B]; chunk j of row r
// (k = s*32 + j*8 ..+7, col n = bn*128+r) stored at slot j ^ swz4(r).
__global__ __launch_bounds__(256)
void cvtW_kernel(const float* __restrict__ W, uint8_t* __restrict__ Wt) {
  const int c    = blockIdx.x * 256 + threadIdx.x;   // 0..32767
  const int j    = c & 3;
  const int r    = (c >> 2) & 127;
  const int tile = c >> 9;                           // bn*16 + s, 0..63
  const int s    = tile & 15;
  const int bn   = tile >> 4;
  const int n    = bn * 128 + r;
  const int k0   = s * 32 + j * 8;
  float e[8];
#pragma unroll
  for (int i = 0; i < 8; ++i) e[i] = W[(size_t)(k0 + i) * NTOT + n];
  uint4 v = make_uint4(pk2(e[0], e[1]), pk2(e[2], e[3]),
                       pk2(e[4], e[5]), pk2(e[6], e[7]));
  *(uint4*)(Wt + ((size_t)tile << 13) + (r << 6) + ((j ^ swz4(r)) << 4)) = v;
}

// ---------------- pass 2: pipelined GEMM + bias + tanh ----------------
__global__ __launch_bounds__(256, 3)
void hotdd_fused(const float* __restrict__ X, const uint8_t* __restrict__ Wt,
                 const float* __restrict__ Bv, float* __restrict__ Y) {
  __shared__ uint8_t Ab0[8192], Ab1[8192], Bb0[8192], Bb1[8192];

  // XCD swizzle: the 4 bn-blocks sharing an X strip -> same XCD, adjacent.
  const int d  = blockIdx.x;
  const int bm = ((d >> 5) << 3) | (d & 7);   // 0..511
  const int bn = (d >> 3) & 3;                // 0..3

  const int tid  = threadIdx.x;
  const int lane = tid & 63;
  const int wv   = tid >> 6;
  const int wr   = (wv >> 1) * 64;
  const int wc   = (wv & 1) * 64;
  const int lo5  = lane & 31;
  const int hi1  = lane >> 5;

  // ---- A staging map: lane -> row arow = wv*32 + (lane>>1), k-half ahalf.
  const int arow  = wv * 32 + (lane >> 1);
  const int ahalf = lane & 1;
  const float* pA = X + (size_t)(bm * 128 + arow) * KTOT + ahalf * 16;
  const int ak  = swz4(arow);
  const int aw0 = arow * 64 + ((((ahalf << 1) | 0) ^ ak) << 4);
  const int aw1 = arow * 64 + ((((ahalf << 1) | 1) ^ ak) << 4);

  // ---- B staging: wave wv copies bytes [wv*2048, +2048) of the 8KB tile.
  const uint8_t* pB = Wt + ((size_t)(bn * 16) << 13) + wv * 2048 + lane * 16;
  uint8_t* Bd0 = Bb0 + wv * 2048;   // wave-uniform; HW adds lane*16
  uint8_t* Bd1 = Bb1 + wv * 2048;

  // ---- fragment read offsets (64B rows, swizzled slots)
  const int rA0 = wr + lo5, rA1 = rA0 + 32;
  const int rB0 = wc + lo5, rB1 = rB0 + 32;
  const int oA0 = rA0 * 64, oA1 = rA1 * 64;
  const int oB0 = rB0 * 64, oB1 = rB1 * 64;
  const int kA0 = swz4(rA0), kA1 = swz4(rA1);
  const int kB0 = swz4(rB0), kB1 = swz4(rB1);

  // 4 rotating A-prefetch reg sets (named -> static indexing, rule #20)
  float4 s0_0, s0_1, s0_2, s0_3;
  float4 s1_0, s1_1, s1_2, s1_3;
  float4 s2_0, s2_1, s2_2, s2_3;
  float4 s3_0, s3_1, s3_2, s3_3;
  f32x16 acc00 = {}, acc01 = {}, acc10 = {}, acc11 = {};

#define SEP() asm volatile("" ::: "memory")
#define VM(N)  asm volatile("s_waitcnt vmcnt(" #N ")" ::: "memory")
#define LGKM0() asm volatile("s_waitcnt lgkmcnt(0)" ::: "memory")

#define BGLDS(BD, S) do {                                                     \
    const uint8_t* bs_ = pB + ((size_t)(S) << 13);                            \
    __builtin_amdgcn_global_load_lds((glb8*)bs_, (lds8*)(BD), 16, 0, 0);      \
    __builtin_amdgcn_global_load_lds((glb8*)(bs_ + 1024),                     \
                                     (lds8*)((BD) + 1024), 16, 0, 0);         \
    SEP();                                                                    \
  } while (0)

#define LOADA(R0, R1, R2, R3, S) do {                                         \
    const float* ap_ = pA + (S) * 32;                                         \
    R0 = *(const float4*)(ap_ + 0);  R1 = *(const float4*)(ap_ + 4);          \
    R2 = *(const float4*)(ap_ + 8);  R3 = *(const float4*)(ap_ + 12);         \
    SEP();                                                                    \
  } while (0)

#define CVTA(R0, R1, R2, R3, AB) do {                                         \
    *(uint4*)((AB) + aw0) = make_uint4(pk2(R0.x, R0.y), pk2(R0.z, R0.w),      \
                                       pk2(R1.x, R1.y), pk2(R1.z, R1.w));     \
    *(uint4*)((AB) + aw1) = make_uint4(pk2(R2.x, R2.y), pk2(R2.z, R2.w),      \
                                       pk2(R3.x, R3.y), pk2(R3.z, R3.w));     \
  } while (0)

#define MFMA_STEP(AB, BB) do {                                                \
    _Pragma("unroll")                                                         \
    for (int kk = 0; kk < 2; ++kk) {                                          \
      const int c_ = (kk << 1) | hi1;                                         \
      bf16x8 fa0 = *(const bf16x8*)((AB) + oA0 + ((c_ ^ kA0) << 4));          \
      bf16x8 fa1 = *(const bf16x8*)((AB) + oA1 + ((c_ ^ kA1) << 4));          \
      bf16x8 fb0 = *(const bf16x8*)((BB) + oB0 + ((c_ ^ kB0) << 4));          \
      bf16x8 fb1 = *(const bf16x8*)((BB) + oB1 + ((c_ ^ kB1) << 4));          \
      acc00 = __builtin_amdgcn_mfma_f32_32x32x16_bf16(fa0, fb0, acc00, 0,0,0);\
      acc01 = __builtin_amdgcn_mfma_f32_32x32x16_bf16(fa0, fb1, acc01, 0,0,0);\
      acc10 = __builtin_amdgcn_mfma_f32_32x32x16_bf16(fa1, fb0, acc10, 0,0,0);\
      acc11 = __builtin_amdgcn_mfma_f32_32x32x16_bf16(fa1, fb1, acc11, 0,0,0);\
    }                                                                         \
  } while (0)

// One K-step t:
//   VM(4): retires A(t+1), A(t+2), B(t) (issue order: A's older than B(t));
//          leaves A(t+3) in flight.
//   barrier: with per-wave B(t) retired -> all waves' B(t) visible in LDS.
//   BGLDS(t+1) -> other B buf (last read t-1, drained via LGKM0+this barrier)
//   LOADA(t+4) -> set (t&3) (its A(t) was CVTA'd at step t-1 -> free)
//   MFMA(t); CVTA(A(t+1)) -> other A buf (A(t+1) retired by VM(4), no wait)
#define STEPX(T, ABC, BBC, ABW, BBW, L0,L1,L2,L3, C0,C1,C2,C3) do {           \
    VM(4);                                                                    \
    __builtin_amdgcn_s_barrier();                                             \
    BGLDS(BBW, (T) + 1);                                                      \
    LOADA(L0, L1, L2, L3, (T) + 4);                                           \
    MFMA_STEP(ABC, BBC);                                                      \
    CVTA(C0, C1, C2, C3, ABW);                                                \
    LGKM0();                                                                  \
  } while (0)

  // ---- prologue: A0..A3 + B0 in flight; CVT A0 -> Ab0.
  LOADA(s0_0, s0_1, s0_2, s0_3, 0);
  LOADA(s1_0, s1_1, s1_2, s1_3, 1);
  LOADA(s2_0, s2_1, s2_2, s2_3, 2);
  BGLDS(Bd0, 0);
  LOADA(s3_0, s3_1, s3_2, s3_3, 3);
  VM(14);                           // retires A0
  CVTA(s0_0, s0_1, s0_2, s0_3, Ab0);
  LGKM0();

  // ---- main loop: steps 0..11 (period-4 set rotation, period-2 buffers)
#pragma unroll 1
  for (int it = 0; it < 3; ++it) {
    const int t4 = it << 2;
    STEPX(t4 + 0, Ab0, Bb0, Ab1, Bd1, s0_0,s0_1,s0_2,s0_3, s1_0,s1_1,s1_2,s1_3);
    STEPX(t4 + 1, Ab1, Bb1, Ab0, Bd0, s1_0,s1_1,s1_2,s1_3, s2_0,s2_1,s2_2,s2_3);
    STEPX(t4 + 2, Ab0, Bb0, Ab1, Bd1, s2_0,s2_1,s2_2,s2_3, s3_0,s3_1,s3_2,s3_3);
    STEPX(t4 + 3, Ab1, Bb1, Ab0, Bd0, s3_0,s3_1,s3_2,s3_3, s0_0,s0_1,s0_2,s0_3);
  }

  // ---- tails t=12..15 (no more A loads; exact counts)
  // t=12: queue [A13,A14,B12,A15]=14 -> VM(4) leaves A15.
  VM(4);
  __builtin_amdgcn_s_barrier();
  BGLDS(Bd1, 13);
  MFMA_STEP(Ab0, Bb0);
  CVTA(s1_0, s1_1, s1_2, s1_3, Ab1);      // A13
  LGKM0();
  // t=13: queue [A15, B13] -> need B13 -> VM(0).
  VM(0);
  __builtin_amdgcn_s_barrier();
  BGLDS(Bd0, 14);
  MFMA_STEP(Ab1, Bb1);
  CVTA(s2_0, s2_1, s2_2, s2_3, Ab0);      // A14
  LGKM0();
  // t=14: queue [B14] -> VM(0).
  VM(0);
  __builtin_amdgcn_s_barrier();
  BGLDS(Bd1, 15);
  MFMA_STEP(Ab0, Bb0);
  CVTA(s3_0, s3_1, s3_2, s3_3, Ab1);      // A15
  LGKM0();
  // t=15: queue [B15] -> VM(0).
  VM(0);
  __builtin_amdgcn_s_barrier();
  MFMA_STEP(Ab1, Bb1);

  // ---- epilogue: bias + tanh + fp32 store
  const int gn0 = bn * 128 + wc + lo5;
  const int gn1 = gn0 + 32;
  const float bv0 = Bv[gn0];
  const float bv1 = Bv[gn1];

#define EPI(ACC, MI, GN, BVAL) do {                                           \
    _Pragma("unroll")                                                         \
    for (int r = 0; r < 16; ++r) {                                            \
      const int mloc = wr + (MI) * 32 + (hi1 << 2) + ((r >> 2) << 3) + (r & 3);\
      Y[(size_t)(bm * 128 + mloc) * NTOT + (GN)] = fast_tanh((ACC)[r] + (BVAL));\
    }                                                                         \
  } while (0)

  EPI(acc00, 0, gn0, bv0);
  EPI(acc01, 0, gn1, bv1);
  EPI(acc10, 1, gn0, bv0);
  EPI(acc11, 1, gn1, bv1);
}

// ---------------- fallback: R1 kernel (146us), used if ws too small ----------
struct Regs {
  float4 a0,a1,a2,a3,a4,a5,a6,a7;
  float4 u0,u1,u2,u3;
  float4 v0,v1,v2,v3;
};

__global__ __launch_bounds__(256, 2)
void hotdd_fallback(const float* __restrict__ X, const float* __restrict__ W,
                    const float* __restrict__ Bv, float* __restrict__ Y) {
  __shared__ char Ab[128 * 64 * 2];
  __shared__ char Bb[128 * 64 * 2];
  const int d  = blockIdx.x;
  const int bm = ((d >> 5) << 3) | (d & 7);
  const int bn = (d >> 3) & 3;
  const int tid  = threadIdx.x;
  const int lane = tid & 63;
  const int wv   = tid >> 6;
  const int wr   = (wv >> 1) * 64;
  const int wc   = (wv & 1) * 64;
  const int lo5  = lane & 31;
  const int hi1  = lane >> 5;
  const int rs   = lo5 & 7;
  const int am   = tid >> 1;
  const int ah   = tid & 1;
  const int amz  = am & 7;
  const int abase = am * 128;
  const float* Ag = X + (size_t)(bm * 128 + am) * KTOT + ah * 32;
  const int kp = lo5;
  const int ng = wv * 32 + hi1 * 16;
  const float* Bg = W + (size_t)(2 * kp) * NTOT + bn * 128 + ng;

#define LOADR(R, K0) do {                                                     \
    const float* ap_ = Ag + (K0);                                             \
    R.a0 = *(const float4*)(ap_ +  0); R.a1 = *(const float4*)(ap_ +  4);     \
    R.a2 = *(const float4*)(ap_ +  8); R.a3 = *(const float4*)(ap_ + 12);     \
    R.a4 = *(const float4*)(ap_ + 16); R.a5 = *(const float4*)(ap_ + 20);     \
    R.a6 = *(const float4*)(ap_ + 24); R.a7 = *(const float4*)(ap_ + 28);     \
    const float* bp_ = Bg + (size_t)(K0) * NTOT;                              \
    R.u0 = *(const float4*)(bp_ +  0); R.u1 = *(const float4*)(bp_ +  4);     \
    R.u2 = *(const float4*)(bp_ +  8); R.u3 = *(const float4*)(bp_ + 12);     \
    R.v0 = *(const float4*)(bp_ + NTOT +  0); R.v1 = *(const float4*)(bp_ + NTOT +  4); \
    R.v2 = *(const float4*)(bp_ + NTOT +  8); R.v3 = *(const float4*)(bp_ + NTOT + 12); \
  } while (0)

#define ASTF(R, J, P, Q)                                                      \
    *(uint4*)(Ab + abase + (((((ah << 2) + (J)) ^ amz)) << 4)) =              \
      make_uint4(pk2(R.P.x, R.P.y), pk2(R.P.z, R.P.w),                        \
                 pk2(R.Q.x, R.Q.y), pk2(R.Q.z, R.Q.w));
#define BSTF(R, I, UV, C)                                                     \
    *(uint32_t*)(Bb + (ng + (I)) * 128 + ((kp << 2) ^ (((I) & 7) << 4))) =    \
      pk2(R.u##UV.C, R.v##UV.C);

#define STORERF(R) do {                                                       \
    ASTF(R, 0, a0, a1) ASTF(R, 1, a2, a3) ASTF(R, 2, a4, a5) ASTF(R, 3, a6, a7)\
    BSTF(R, 0, 0, x) BSTF(R, 1, 0, y) BSTF(R, 2, 0, z) BSTF(R, 3, 0, w)       \
    BSTF(R, 4, 1, x) BSTF(R, 5, 1, y) BSTF(R, 6, 1, z) BSTF(R, 7, 1, w)       \
    BSTF(R, 8, 2, x) BSTF(R, 9, 2, y) BSTF(R,10, 2, z) BSTF(R,11, 2, w)       \
    BSTF(R,12, 3, x) BSTF(R,13, 3, y) BSTF(R,14, 3, z) BSTF(R,15, 3, w)       \
  } while (0)

  f32x16 acc00 = {}, acc01 = {}, acc10 = {}, acc11 = {};
  const char* Ard0 = Ab + (wr + lo5) * 128;
  const char* Ard1 = Ard0 + 32 * 128;
  const char* Brd0 = Bb + (wc + lo5) * 128;
  const char* Brd1 = Brd0 + 32 * 128;

#define MFMA_PHASE_F() do {                                                   \
    _Pragma("unroll")                                                         \
    for (int kk = 0; kk < 4; ++kk) {                                          \
      const int sb = ((((kk << 1) | hi1) ^ rs) << 4);                         \
      bf16x8 fa0 = *(const bf16x8*)(Ard0 + sb);                               \
      bf16x8 fa1 = *(const bf16x8*)(Ard1 + sb);                               \
      bf16x8 fb0 = *(const bf16x8*)(Brd0 + sb);                               \
      bf16x8 fb1 = *(const bf16x8*)(Brd1 + sb);                               \
      acc00 = __builtin_amdgcn_mfma_f32_32x32x16_bf16(fa0, fb0, acc00, 0,0,0);\
      acc01 = __builtin_amdgcn_mfma_f32_32x32x16_bf16(fa0, fb1, acc01, 0,0,0);\
      acc10 = __builtin_amdgcn_mfma_f32_32x32x16_bf16(fa1, fb0, acc10, 0,0,0);\
      acc11 = __builtin_amdgcn_mfma_f32_32x32x16_bf16(fa1, fb1, acc11, 0,0,0);\
    }                                                                         \
  } while (0)

  Regs r0, r1;
  LOADR(r0, 0);
#pragma unroll 1
  for (int s = 0; s < 8; s += 2) {
    STORERF(r0);
    __syncthreads();
    LOADR(r1, (s + 1) * 64);
    MFMA_PHASE_F();
    __syncthreads();
    STORERF(r1);
    __syncthreads();
    if (s + 2 < 8) LOADR(r0, (s + 2) * 64);
    MFMA_PHASE_F();
    __syncthreads();
  }

  const int gn0 = bn * 128 + wc + lo5;
  const int gn1 = gn0 + 32;
  const float bv0 = Bv[gn0];
  const float bv1 = Bv[gn1];

#define EPIF(ACC, MI, GN, BVAL) do {                                          \
    _Pragma("unroll")                                                         \
    for (int r = 0; r < 16; ++r) {                                            \
      const int mloc = wr + (MI) * 32 + (hi1 << 2) + ((r >> 2) << 3) + (r & 3);\
      Y[(size_t)(bm * 128 + mloc) * NTOT + (GN)] = fast_tanh((ACC)[r] + (BVAL));\
    }                                                                         \
  } while (0)

  EPIF(acc00, 0, gn0, bv0);
  EPIF(acc01, 0, gn1, bv1);
  EPIF(acc10, 1, gn0, bv0);
  EPIF(acc11, 1, gn1, bv1);
}

extern "C" void kernel_launch(void* const* d_in, const int* in_sizes, int n_in,
                              void* d_out, int out_size, void* d_ws, size_t ws_size,
                              hipStream_t stream) {
  (void)in_sizes; (void)n_in; (void)out_size;
  const float* X = (const float*)d_in[0];
  const float* W = (const float*)d_in[1];
  const float* b = (const float*)d_in[2];
  float* Y = (float*)d_out;
  if (ws_size >= WS_NEEDED) {
    uint8_t* Wt = (uint8_t*)d_ws;
    hipLaunchKernelGGL(cvtW_kernel, dim3(128),  dim3(256), 0, stream, W, Wt);
    hipLaunchKernelGGL(hotdd_fused, dim3(2048), dim3(256), 0, stream, X, Wt, b, Y);
  } else {
    hipLaunchKernelGGL(hotdd_fallback, dim3(2048), dim3(256), 0, stream, X, W, b, Y);
  }
}

// Round 15
// 72.025 us; speedup vs baseline: 1.3260x; 1.1156x over previous
//
#include <hip/hip_runtime.h>
#include <stdint.h>

// Y = tanh(X @ W + b):  M=65536 (8*64*128), K=512, N=512, all fp32.
// R15: ONE-SHOT A-STAGING, ZERO-BARRIER K-LOOP.
// Frame shift after R7-R14 all pinned at 78-95us / MfmaUtil 13%: the per-step
// A-staging loop (barrier convoy + cvt VALU + staging regs vs 128-reg cliff)
// was the box. Block = 64 M-rows x N=512 x K=512: whole A-panel (64x512 bf16
// = 64KB) staged ONCE into LDS (coalesced fp32->pk2->swizzled write, depth-2
// vmcnt pipeline), one __syncthreads, then 32 k16-iterations of pure
// {4 coalesced B-loads from L2-hot fragment image + 2 swizzled ds_read_b128
// + 8 MFMA}. No barriers, no LDS writes, no cvt in loop. B depth-2 (VM(8),
// 3 rotating reg sets). 4 waves each own an N-quarter (128 cols);
// acc = 8 x f32x16 = 128 AGPR; ~90 VGPR + 128 AGPR <= 256 @ (256,2).
// X read once globally (1024 M-blocks, no bn redundancy); W image 512KB
// L2-resident; Y once -> 268MB ~ 43us floor. MFMA floor 3.4us/CU.
// A-swizzle slot = chunk ^ row (row<64, chunk<64): uniform granule spread
// on write (per-wave-instr single row) and read (bijective over 32 lanes).

typedef short bf16x8 __attribute__((ext_vector_type(8)));
typedef float f32x16 __attribute__((ext_vector_type(16)));

#define KTOT 512
#define NTOT 512
#define WT_BYTES   524288ull      // 512*512*2
#define WS_NEEDED  WT_BYTES

__device__ __forceinline__ uint32_t pk2(float a, float b) {
  uint16_t lo = __builtin_bit_cast(uint16_t, (__bf16)a);   // RNE
  uint16_t hi = __builtin_bit_cast(uint16_t, (__bf16)b);
  return (uint32_t)lo | ((uint32_t)hi << 16);
}

__device__ __forceinline__ float fast_tanh(float z) {
  float t = __builtin_amdgcn_exp2f(z * 2.8853900817779268f);
  return 1.0f - 2.0f * __builtin_amdgcn_rcpf(t + 1.0f);
}

#define MFMA(A, B, C) __builtin_amdgcn_mfma_f32_32x32x16_bf16(A, B, C, 0, 0, 0)

// ---- pass 1: W fp32 [k][n] -> bf16 fragment-order image ----
// 16B chunk c: lane=c&63, nf=(c>>6)&3, k16=(c>>8)&31, wq=c>>13.
// col = wq*128 + nf*32 + (lane&31); k = k16*16 + (lane>>5)*8 + [0..7].
// byte addr = wq*131072 + k16*4096 + nf*1024 + lane*16.
__global__ __launch_bounds__(256)
void cvtW_kernel(const float* __restrict__ W, uint8_t* __restrict__ Wt) {
  const int c    = blockIdx.x * 256 + threadIdx.x;   // 0..32767
  const int lane = c & 63;
  const int nf   = (c >> 6) & 3;
  const int k16  = (c >> 8) & 31;
  const int wq   = c >> 13;
  const int col  = wq * 128 + nf * 32 + (lane & 31);
  const int kb   = k16 * 16 + (lane >> 5) * 8;
  float e[8];
#pragma unroll
  for (int i = 0; i < 8; ++i) e[i] = W[(size_t)(kb + i) * NTOT + col];
  *(uint4*)(Wt + (size_t)c * 16) =
      make_uint4(pk2(e[0], e[1]), pk2(e[2], e[3]),
                 pk2(e[4], e[5]), pk2(e[6], e[7]));
}

// ---------------- pass 2: one-shot-staged GEMM + bias + tanh ----------------
__global__ __launch_bounds__(256, 2)
void hotdd_fused(const float* __restrict__ X, const uint8_t* __restrict__ Wt,
                 const float* __restrict__ Bv, float* __restrict__ Y) {
  __shared__ uint8_t Ab[65536];   // A panel [64 rows][512 k] bf16, swizzled:
                                  // 16B chunk cRow stored at slot c ^ row

  const int bm   = blockIdx.x;          // 0..1023 (64-row strips)
  const int tid  = threadIdx.x;
  const int lane = tid & 63;
  const int wv   = tid >> 6;
  const int lo5  = lane & 31;
  const int hi1  = lane >> 5;

#define SEP() asm volatile("" ::: "memory")
#define VM(N) asm volatile("s_waitcnt vmcnt(" #N ")" ::: "memory")

  // ==== prologue: stage A panel (128KB fp32 -> 64KB bf16 LDS), once ====
  // batch B covers fp32 elems [B*4096, +4096): thread loads 4 float4s at
  // q = Xs + B*4096 + tid*4 (+1024 apart) -> row = 2*(4B+i) + (tid>>7),
  // col = (tid&127)*4 -> chunk = (tid>>1)&63, half = tid&1.
  const float* Xs = X + (size_t)bm * (64 * KTOT);
  const int chunkT = (tid >> 1) & 63;
  const int halfT  = tid & 1;
  const int rbT    = tid >> 7;

  float4 p00, p01, p02, p03, p10, p11, p12, p13;

#define LOADP(R0, R1, R2, R3, B) do {                                         \
    const float* q_ = Xs + (size_t)(B) * 4096 + tid * 4;                      \
    R0 = *(const float4*)q_;          R1 = *(const float4*)(q_ + 1024);       \
    R2 = *(const float4*)(q_ + 2048); R3 = *(const float4*)(q_ + 3072);       \
    SEP();                                                                    \
  } while (0)

#define CVTP1(R, J) do {                                                      \
    const int row_ = 2 * (J) + rbT;                                           \
    *(uint2*)(Ab + row_ * 1024 + ((chunkT ^ row_) << 4) + halfT * 8) =        \
        make_uint2(pk2(R.x, R.y), pk2(R.z, R.w));                             \
  } while (0)
#define CVTP(R0, R1, R2, R3, B) do {                                          \
    CVTP1(R0, 4 * (B));     CVTP1(R1, 4 * (B) + 1);                           \
    CVTP1(R2, 4 * (B) + 2); CVTP1(R3, 4 * (B) + 3);  SEP();                   \
  } while (0)

  LOADP(p00, p01, p02, p03, 0);
  LOADP(p10, p11, p12, p13, 1);
  VM(4); CVTP(p00, p01, p02, p03, 0); LOADP(p00, p01, p02, p03, 2);
  VM(4); CVTP(p10, p11, p12, p13, 1); LOADP(p10, p11, p12, p13, 3);
  VM(4); CVTP(p00, p01, p02, p03, 2); LOADP(p00, p01, p02, p03, 4);
  VM(4); CVTP(p10, p11, p12, p13, 3); LOADP(p10, p11, p12, p13, 5);
  VM(4); CVTP(p00, p01, p02, p03, 4); LOADP(p00, p01, p02, p03, 6);
  VM(4); CVTP(p10, p11, p12, p13, 5); LOADP(p10, p11, p12, p13, 7);
  VM(4); CVTP(p00, p01, p02, p03, 6);
  VM(0); CVTP(p10, p11, p12, p13, 7);

  // ==== B prefetch bootstrap (in flight across the barrier) ====
  const uint8_t* pBw = Wt + (size_t)wv * 131072 + lane * 16;
  bf16x8 e0, e1, e2, e3, o0, o1, o2, o3, f0, f1, f2, f3;

#define LOADB(S0, S1, S2, S3, T) do {                                         \
    const uint8_t* q_ = pBw + (size_t)(T) * 4096;                             \
    S0 = *(const bf16x8*)q_;            S1 = *(const bf16x8*)(q_ + 1024);     \
    S2 = *(const bf16x8*)(q_ + 2048);   S3 = *(const bf16x8*)(q_ + 3072);     \
    SEP();                                                                    \
  } while (0)

  LOADB(e0, e1, e2, e3, 0);
  LOADB(o0, o1, o2, o3, 1);
  __syncthreads();                 // all A writes visible; one barrier total

  // ==== K-loop: 32 k16 steps, no barriers, no LDS writes ====
  f32x16 c00 = {}, c01 = {}, c02 = {}, c03 = {};
  f32x16 c10 = {}, c11 = {}, c12 = {}, c13 = {};
  const int ardA = lo5 << 10;            // row lo5
  const int ardB = (lo5 + 32) << 10;     // row lo5+32

#define COMP(T, S0, S1, S2, S3) do {                                          \
    const int cb_ = (((((T) << 1) | hi1)) ^ lo5) << 4;                        \
    bf16x8 fa0 = *(const bf16x8*)(Ab + ardA + cb_);                           \
    bf16x8 fa1 = *(const bf16x8*)(Ab + ardB + (cb_ ^ 512));                   \
    c00 = MFMA(fa0, S0, c00);  c01 = MFMA(fa0, S1, c01);                      \
    c02 = MFMA(fa0, S2, c02);  c03 = MFMA(fa0, S3, c03);                      \
    c10 = MFMA(fa1, S0, c10);  c11 = MFMA(fa1, S1, c11);                      \
    c12 = MFMA(fa1, S2, c12);  c13 = MFMA(fa1, S3, c13);                      \
  } while (0)

#pragma unroll 1
  for (int t = 0; t < 30; t += 3) {      // sets rotate e,o,f; 2-step B slack
    LOADB(f0, f1, f2, f3, t + 2);  VM(8);  COMP(t,     e0, e1, e2, e3);
    LOADB(e0, e1, e2, e3, t + 3);  VM(8);  COMP(t + 1, o0, o1, o2, o3);
    LOADB(o0, o1, o2, o3, t + 4);  VM(8);  COMP(t + 2, f0, f1, f2, f3);
  }
  VM(4);  COMP(30, e0, e1, e2, e3);
  VM(0);  COMP(31, o0, o1, o2, o3);

  // ==== epilogue: bias + tanh + fp32 store (128B/wave-instr segments) ====
  const int colb = wv * 128 + lo5;
  const float bv0 = Bv[colb];
  const float bv1 = Bv[colb + 32];
  const float bv2 = Bv[colb + 64];
  const float bv3 = Bv[colb + 96];
  const size_t rowbase = (size_t)bm * 64 + (hi1 << 2);

#define EPI(ACC, MI, NF, BV) do {                                             \
    _Pragma("unroll")                                                         \
    for (int r = 0; r < 16; ++r) {                                            \
      const size_t row_ = rowbase + (MI) * 32 + (r & 3) + ((r >> 2) << 3);    \
      Y[row_ * NTOT + colb + (NF) * 32] = fast_tanh((ACC)[r] + (BV));         \
    }                                                                         \
  } while (0)

  EPI(c00, 0, 0, bv0);  EPI(c01, 0, 1, bv1);
  EPI(c02, 0, 2, bv2);  EPI(c03, 0, 3, bv3);
  EPI(c10, 1, 0, bv0);  EPI(c11, 1, 1, bv1);
  EPI(c12, 1, 2, bv2);  EPI(c13, 1, 3, bv3);
}

// ---------------- fallback: R1 kernel (146us), used if ws too small ----------
struct Regs {
  float4 a0,a1,a2,a3,a4,a5,a6,a7;
  float4 u0,u1,u2,u3;
  float4 v0,v1,v2,v3;
};

__global__ __launch_bounds__(256, 2)
void hotdd_fallback(const float* __restrict__ X, const float* __restrict__ W,
                    const float* __restrict__ Bv, float* __restrict__ Y) {
  __shared__ char Ab[128 * 64 * 2];
  __shared__ char Bb[128 * 64 * 2];
  const int d  = blockIdx.x;
  const int bm = ((d >> 5) << 3) | (d & 7);
  const int bn = (d >> 3) & 3;
  const int tid  = threadIdx.x;
  const int lane = tid & 63;
  const int wv   = tid >> 6;
  const int wr   = (wv >> 1) * 64;
  const int wc   = (wv & 1) * 64;
  const int lo5  = lane & 31;
  const int hi1  = lane >> 5;
  const int rs   = lo5 & 7;
  const int am   = tid >> 1;
  const int ah   = tid & 1;
  const int amz  = am & 7;
  const int abase = am * 128;
  const float* Ag = X + (size_t)(bm * 128 + am) * KTOT + ah * 32;
  const int kp = lo5;
  const int ng = wv * 32 + hi1 * 16;
  const float* Bg = W + (size_t)(2 * kp) * NTOT + bn * 128 + ng;

#define LOADR(R, K0) do {                                                     \
    const float* ap_ = Ag + (K0);                                             \
    R.a0 = *(const float4*)(ap_ +  0); R.a1 = *(const float4*)(ap_ +  4);     \
    R.a2 = *(const float4*)(ap_ +  8); R.a3 = *(const float4*)(ap_ + 12);     \
    R.a4 = *(const float4*)(ap_ + 16); R.a5 = *(const float4*)(ap_ + 20);     \
    R.a6 = *(const float4*)(ap_ + 24); R.a7 = *(const float4*)(ap_ + 28);     \
    const float* bp_ = Bg + (size_t)(K0) * NTOT;                              \
    R.u0 = *(const float4*)(bp_ +  0); R.u1 = *(const float4*)(bp_ +  4);     \
    R.u2 = *(const float4*)(bp_ +  8); R.u3 = *(const float4*)(bp_ + 12);     \
    R.v0 = *(const float4*)(bp_ + NTOT +  0); R.v1 = *(const float4*)(bp_ + NTOT +  4); \
    R.v2 = *(const float4*)(bp_ + NTOT +  8); R.v3 = *(const float4*)(bp_ + NTOT + 12); \
  } while (0)

#define ASTF(R, J, P, Q)                                                      \
    *(uint4*)(Ab + abase + (((((ah << 2) + (J)) ^ amz)) << 4)) =              \
      make_uint4(pk2(R.P.x, R.P.y), pk2(R.P.z, R.P.w),                        \
                 pk2(R.Q.x, R.Q.y), pk2(R.Q.z, R.Q.w));
#define BSTF(R, I, UV, C)                                                     \
    *(uint32_t*)(Bb + (ng + (I)) * 128 + ((kp << 2) ^ (((I) & 7) << 4))) =    \
      pk2(R.u##UV.C, R.v##UV.C);

#define STORERF(R) do {                                                       \
    ASTF(R, 0, a0, a1) ASTF(R, 1, a2, a3) ASTF(R, 2, a4, a5) ASTF(R, 3, a6, a7)\
    BSTF(R, 0, 0, x) BSTF(R, 1, 0, y) BSTF(R, 2, 0, z) BSTF(R, 3, 0, w)       \
    BSTF(R, 4, 1, x) BSTF(R, 5, 1, y) BSTF(R, 6, 1, z) BSTF(R, 7, 1, w)       \
    BSTF(R, 8, 2, x) BSTF(R, 9, 2, y) BSTF(R,10, 2, z) BSTF(R,11, 2, w)       \
    BSTF(R,12, 3, x) BSTF(R,13, 3, y) BSTF(R,14, 3, z) BSTF(R,15, 3, w)       \
  } while (0)

  f32x16 acc00 = {}, acc01 = {}, acc10 = {}, acc11 = {};
  const char* Ard0 = Ab + (wr + lo5) * 128;
  const char* Ard1 = Ard0 + 32 * 128;
  const char* Brd0 = Bb + (wc + lo5) * 128;
  const char* Brd1 = Brd0 + 32 * 128;

#define MFMA_PHASE_F() do {                                                   \
    _Pragma("unroll")                                                         \
    for (int kk = 0; kk < 4; ++kk) {                                          \
      const int sb = ((((kk << 1) | hi1) ^ rs) << 4);                         \
      bf16x8 fa0 = *(const bf16x8*)(Ard0 + sb);                               \
      bf16x8 fa1 = *(const bf16x8*)(Ard1 + sb);                               \
      bf16x8 fb0 = *(const bf16x8*)(Brd0 + sb);                               \
      bf16x8 fb1 = *(const bf16x8*)(Brd1 + sb);                               \
      acc00 = MFMA(fa0, fb0, acc00);  acc01 = MFMA(fa0, fb1, acc01);          \
      acc10 = MFMA(fa1, fb0, acc10);  acc11 = MFMA(fa1, fb1, acc11);          \
    }                                                                         \
  } while (0)

  Regs r0, r1;
  LOADR(r0, 0);
#pragma unroll 1
  for (int s = 0; s < 8; s += 2) {
    STORERF(r0);
    __syncthreads();
    LOADR(r1, (s + 1) * 64);
    MFMA_PHASE_F();
    __syncthreads();
    STORERF(r1);
    __syncthreads();
    if (s + 2 < 8) LOADR(r0, (s + 2) * 64);
    MFMA_PHASE_F();
    __syncthreads();
  }

  const int gn0 = bn * 128 + wc + lo5;
  const int gn1 = gn0 + 32;
  const float bv0 = Bv[gn0];
  const float bv1 = Bv[gn1];

#define EPIF(ACC, MI, GN, BVAL) do {                                          \
    _Pragma("unroll")                                                         \
    for (int r = 0; r < 16; ++r) {                                            \
      const int mloc = wr + (MI) * 32 + (hi1 << 2) + ((r >> 2) << 3) + (r & 3);\
      Y[(size_t)(bm * 128 + mloc) * NTOT + (GN)] = fast_tanh((ACC)[r] + (BVAL));\
    }                                                                         \
  } while (0)

  EPIF(acc00, 0, gn0, bv0);
  EPIF(acc01, 0, gn1, bv1);
  EPIF(acc10, 1, gn0, bv0);
  EPIF(acc11, 1, gn1, bv1);
}

extern "C" void kernel_launch(void* const* d_in, const int* in_sizes, int n_in,
                              void* d_out, int out_size, void* d_ws, size_t ws_size,
                              hipStream_t stream) {
  (void)in_sizes; (void)n_in; (void)out_size;
  const float* X = (const float*)d_in[0];
  const float* W = (const float*)d_in[1];
  const float* b = (const float*)d_in[2];
  float* Y = (float*)d_out;
  if (ws_size >= WS_NEEDED) {
    uint8_t* Wt = (uint8_t*)d_ws;
    hipLaunchKernelGGL(cvtW_kernel, dim3(128),  dim3(256), 0, stream, W, Wt);
    hipLaunchKernelGGL(hotdd_fused, dim3(1024), dim3(256), 0, stream, X, Wt, b, Y);
  } else {
    hipLaunchKernelGGL(hotdd_fallback, dim3(2048), dim3(256), 0, stream, X, W, b, Y);
  }
}